// Round 16
// baseline (664.932 us; speedup 1.0000x reference)
//
#include <hip/hip_runtime.h>

#define NLAYER 3
#define NATOM 20000
#define NPROBE 100000
#define NEDGE 400000
#define HD 128
#define NBIN 2048
#define CUTOFFF 4.0f
#define PLANE 16384   // ushorts per bf16 plane (128x128)
#define MT 64         // row tile
#define NT 512        // threads per block (8 waves)
#define NSBLK ((NPROBE + 255) / 256)   // 391 scan blocks

typedef unsigned int u32;
typedef unsigned short u16;
typedef __attribute__((ext_vector_type(8))) short bf16x8;
typedef __attribute__((ext_vector_type(4))) float f32x4;

// ---------- math helpers ----------
__device__ __forceinline__ float sspf(float x) {
    float e = __builtin_amdgcn_exp2f(fminf(x, 80.f) * 1.44269504088896341f);
    return 0.69314718055994531f * (__builtin_amdgcn_logf(1.f + e) - 1.f);
}
__device__ __forceinline__ float sigf(float x) {
    return 1.f / (1.f + __builtin_amdgcn_exp2f(-x * 1.44269504088896341f));
}
__device__ __forceinline__ void atomic_add_f(float* p, float v) {
    __hip_atomic_fetch_add(p, v, __ATOMIC_RELAXED, __HIP_MEMORY_SCOPE_AGENT);
}
__device__ __forceinline__ u32 atomic_add_u(u32* p, u32 v) {
    return __hip_atomic_fetch_add(p, v, __ATOMIC_RELAXED, __HIP_MEMORY_SCOPE_AGENT);
}
__device__ __forceinline__ u32 f2u(float f) { union { float f; u32 u; } x; x.f = f; return x.u; }
__device__ __forceinline__ float u2f(u32 u) { union { float f; u32 u; } x; x.u = u; return x.f; }
__device__ __forceinline__ u16 bf16rn(float f) {
    u32 u = f2u(f);
    u32 r = u + 0x7fffu + ((u >> 16) & 1u);
    return (u16)(r >> 16);
}
__device__ __forceinline__ u32 bf16pair(float x, float y) {
    u32 ux = f2u(x);
    u32 hx = (ux + 0x7fffu + ((ux >> 16) & 1u)) >> 16;
    u32 uy = f2u(y);
    u32 hy = (uy + 0x7fffu + ((uy >> 16) & 1u)) & 0xffff0000u;
    return hx | hy;
}
__device__ __forceinline__ void split_pair(float x, float y, u32& hi, u32& lo) {
    u32 ux = f2u(x);
    u32 hx = (ux + 0x7fffu + ((ux >> 16) & 1u)) & 0xffff0000u;
    float lxf = x - u2f(hx);
    u32 uy = f2u(y);
    u32 hy = (uy + 0x7fffu + ((uy >> 16) & 1u)) & 0xffff0000u;
    float lyf = y - u2f(hy);
    hi = (hx >> 16) | hy;
    lo = (f2u(lxf) >> 16) | (f2u(lyf) & 0xffff0000u);
}

// LDS-only barrier: do NOT drain vmcnt (atomics / prefetch loads stay in flight).
__device__ __forceinline__ void bar_lds() {
    asm volatile("s_waitcnt lgkmcnt(0)" ::: "memory");
    __builtin_amdgcn_s_barrier();
}

// bijective XCD-chunked swizzle (m204)
__device__ __forceinline__ int bswz(int b, int nb) {
    int q = nb >> 3, r = nb & 7;
    int x = b & 7, o = b >> 3;
    return (x < r ? x * (q + 1) : r * (q + 1) + (x - r) * q) + o;
}

// ---------- MFMA core: weight-stationary column slice ----------
__device__ __forceinline__ void load_bfrags(const u16* __restrict__ Wb, int lane, int wid,
                                            bf16x8 Bh[4], bf16x8 Bl[4]) {
    const bf16x8* Bhp = (const bf16x8*)Wb;
    const bf16x8* Blp = (const bf16x8*)(Wb + PLANE);
#pragma unroll
    for (int c = 0; c < 4; ++c) {
        Bh[c] = Bhp[(size_t)(c * 8 + wid) * 64 + lane];
        Bl[c] = Blp[(size_t)(c * 8 + wid) * 64 + lane];
    }
}

// 3-term (hi/lo A planes)
__device__ __forceinline__ void mma_slice_pre(const u16* __restrict__ ldsH,
                                              const u16* __restrict__ ldsL,
                                              int lane, const bf16x8 Bh[4], const bf16x8 Bl[4],
                                              f32x4 acc[4]) {
    int l15 = lane & 15, kq = lane >> 4;
#pragma unroll
    for (int m = 0; m < 4; ++m) {
        int row = m * 16 + l15;
        int s = row & 7;
        const u16* hp = ldsH + row * 128;
        const u16* lp = ldsL + row * 128;
#pragma unroll
        for (int c = 0; c < 4; ++c) {
            int off = ((c * 4 + kq) ^ s) << 3;
            bf16x8 Ah = *(const bf16x8*)(hp + off);
            bf16x8 Al = *(const bf16x8*)(lp + off);
            acc[m] = __builtin_amdgcn_mfma_f32_16x16x32_bf16(Ah, Bh[c], acc[m], 0, 0, 0);
            acc[m] = __builtin_amdgcn_mfma_f32_16x16x32_bf16(Al, Bh[c], acc[m], 0, 0, 0);
            acc[m] = __builtin_amdgcn_mfma_f32_16x16x32_bf16(Ah, Bl[c], acc[m], 0, 0, 0);
        }
    }
}
__device__ __forceinline__ void mma_slice(const u16* __restrict__ ldsH,
                                          const u16* __restrict__ ldsL,
                                          int lane, int wid,
                                          const u16* __restrict__ Wb,
                                          f32x4 acc[4]) {
    bf16x8 Bh[4], Bl[4];
    load_bfrags(Wb, lane, wid, Bh, Bl);
    mma_slice_pre(ldsH, ldsL, lane, Bh, Bl, acc);
}

// 2-term (single bf16 A plane, hi/lo B)
__device__ __forceinline__ void mma_slice_a1(const u16* __restrict__ ldsA,
                                             int lane, const bf16x8 Bh[4], const bf16x8 Bl[4],
                                             f32x4 acc[4]) {
    int l15 = lane & 15, kq = lane >> 4;
#pragma unroll
    for (int m = 0; m < 4; ++m) {
        int row = m * 16 + l15;
        int s = row & 7;
        const u16* ap = ldsA + row * 128;
#pragma unroll
        for (int c = 0; c < 4; ++c) {
            int off = ((c * 4 + kq) ^ s) << 3;
            bf16x8 Ah = *(const bf16x8*)(ap + off);
            acc[m] = __builtin_amdgcn_mfma_f32_16x16x32_bf16(Ah, Bh[c], acc[m], 0, 0, 0);
            acc[m] = __builtin_amdgcn_mfma_f32_16x16x32_bf16(Ah, Bl[c], acc[m], 0, 0, 0);
        }
    }
}
__device__ __forceinline__ void mma_w_a1(const u16* __restrict__ ldsA,
                                         int lane, int wid, const u16* __restrict__ Wb,
                                         f32x4 acc[4]) {
    bf16x8 Bh[4], Bl[4];
    load_bfrags(Wb, lane, wid, Bh, Bl);
    mma_slice_a1(ldsA, lane, Bh, Bl, acc);
}

// ---------- staging helpers ----------
__device__ __forceinline__ void pack_store(const float* v, int row, int q,
                                           u16* ldsH, u16* ldsL) {
    int s = row & 7;
#pragma unroll
    for (int h = 0; h < 2; ++h) {
        u32 hv[4], lv[4];
#pragma unroll
        for (int k = 0; k < 4; ++k)
            split_pair(v[8 * h + 2 * k], v[8 * h + 2 * k + 1], hv[k], lv[k]);
        int gc = q * 2 + h;
        int off = row * 128 + ((gc ^ s) << 3);
        *(uint4*)(ldsH + off) = make_uint4(hv[0], hv[1], hv[2], hv[3]);
        *(uint4*)(ldsL + off) = make_uint4(lv[0], lv[1], lv[2], lv[3]);
    }
}
__device__ __forceinline__ void pack_plane(const float* v, int row, int q, u16* ldsA) {
    int s = row & 7;
#pragma unroll
    for (int h = 0; h < 2; ++h) {
        u32 w0 = bf16pair(v[8 * h + 0], v[8 * h + 1]);
        u32 w1 = bf16pair(v[8 * h + 2], v[8 * h + 3]);
        u32 w2 = bf16pair(v[8 * h + 4], v[8 * h + 5]);
        u32 w3 = bf16pair(v[8 * h + 6], v[8 * h + 7]);
        int gc = q * 2 + h;
        *(uint4*)(ldsA + row * 128 + ((gc ^ s) << 3)) = make_uint4(w0, w1, w2, w3);
    }
}
__device__ __forceinline__ void gather_rows(const float* __restrict__ A, int M,
                                            int m0, int t, float* v) {
    int r = t >> 3, q = t & 7;
    int row = m0 + r;
    bool ok = row < M;
    const float4* src = (const float4*)(A + (size_t)row * HD + q * 16);
#pragma unroll
    for (int j = 0; j < 4; ++j) {
        float4 x = ok ? src[j] : make_float4(0.f, 0.f, 0.f, 0.f);
        v[4 * j] = x.x; v[4 * j + 1] = x.y; v[4 * j + 2] = x.z; v[4 * j + 3] = x.w;
    }
}
__device__ __forceinline__ void zero_rows(float* A, int M, int m0, int t) {
    int r = t >> 3, q = t & 7;
    int row = m0 + r;
    if (row < M) {
        float4* dst = (float4*)(A + (size_t)row * HD + q * 16);
        float4 z = make_float4(0.f, 0.f, 0.f, 0.f);
#pragma unroll
        for (int j = 0; j < 4; ++j) dst[j] = z;
    }
}
__device__ __forceinline__ void stage_split(const float* __restrict__ A, int M,
                                            int m0, int t, u16* ldsH, u16* ldsL) {
    float v[16];
    gather_rows(A, M, m0, t, v);
    pack_store(v, t >> 3, t & 7, ldsH, ldsL);
}

// hidden-activation stores
__device__ __forceinline__ void h_store(u16* ldsH, u16* ldsL, int wid, int lane,
                                        const f32x4 acc[4], const float* __restrict__ bias) {
    int l15 = lane & 15, lq = lane >> 4;
    int col = wid * 16 + l15;
    float bb = bias[col];
    int gc = col >> 3, wg = col & 7;
#pragma unroll
    for (int m = 0; m < 4; ++m) {
#pragma unroll
        for (int r = 0; r < 4; ++r) {
            int row = m * 16 + lq * 4 + r;
            float h = sspf(acc[m][r] + bb);
            u32 u = f2u(h);
            u32 hh = (u + 0x7fffu + ((u >> 16) & 1u)) & 0xffff0000u;
            float lf = h - u2f(hh);
            int off = row * 128 + ((gc ^ (row & 7)) << 3) + wg;
            ldsH[off] = (u16)(hh >> 16);
            ldsL[off] = (u16)(f2u(lf) >> 16);
        }
    }
}
__device__ __forceinline__ void h_plane(u16* ldsA, int wid, int lane,
                                        const f32x4 acc[4], const float* __restrict__ bias) {
    int l15 = lane & 15, lq = lane >> 4;
    int col = wid * 16 + l15;
    float bb = bias[col];
    int gc = col >> 3, wg = col & 7;
#pragma unroll
    for (int m = 0; m < 4; ++m) {
#pragma unroll
        for (int r = 0; r < 4; ++r) {
            int row = m * 16 + lq * 4 + r;
            int off = row * 128 + ((gc ^ (row & 7)) << 3) + wg;
            ldsA[off] = bf16rn(sspf(acc[m][r] + bb));
        }
    }
}
__device__ __forceinline__ void v_store(u16* ldsH, u16* ldsL, int wid, int lane,
                                        int m, int r, float val) {
    int l15 = lane & 15, lq = lane >> 4;
    int col = wid * 16 + l15;
    int gc = col >> 3, wg = col & 7;
    int row = m * 16 + lq * 4 + r;
    u32 u = f2u(val);
    u32 hh = (u + 0x7fffu + ((u >> 16) & 1u)) & 0xffff0000u;
    float lf = val - u2f(hh);
    int off = row * 128 + ((gc ^ (row & 7)) << 3) + wg;
    ldsH[off] = (u16)(hh >> 16);
    ldsL[off] = (u16)(f2u(lf) >> 16);
}
__device__ __forceinline__ void v_plane(u16* ldsA, int wid, int lane,
                                        int m, int r, float val) {
    int l15 = lane & 15, lq = lane >> 4;
    int col = wid * 16 + l15;
    int gc = col >> 3, wg = col & 7;
    int row = m * 16 + lq * 4 + r;
    ldsA[row * 128 + ((gc ^ (row & 7)) << 3) + wg] = bf16rn(val);
}

// ---------- weight conversion ----------
__global__ void convert_w_k(const float* __restrict__ Wn1, const float* __restrict__ Wn2,
                            const float* __restrict__ gW1, const float* __restrict__ gW2,
                            const float* __restrict__ tW1, const float* __restrict__ tW2,
                            const float* __restrict__ rW1, u16* __restrict__ Wb) {
    int m = blockIdx.x;
    const float* src;
    if (m < 6)       src = Wn1 + (size_t)(m >> 1) * (2 * HD * HD) + (size_t)(m & 1) * (HD * HD);
    else if (m < 9)  src = Wn2 + (size_t)(m - 6) * HD * HD;
    else if (m < 12) src = gW1 + (size_t)(m - 9) * HD * HD;
    else if (m < 15) src = gW2 + (size_t)(m - 12) * HD * HD;
    else if (m < 18) src = tW1 + (size_t)(m - 15) * HD * HD;
    else if (m < 21) src = tW2 + (size_t)(m - 18) * HD * HD;
    else             src = rW1;
    int t = threadIdx.x;
    int lane = t & 63, nn = t >> 6;
    u16* dh = Wb + (size_t)m * (2 * PLANE);
    u16* dl = dh + PLANE;
    for (int c = 0; c < 4; ++c) {
        for (int hh = 0; hh < 2; ++hh) {
            int n = nn + hh * 4;
            int col = n * 16 + (lane & 15);
            int k0 = c * 32 + (lane >> 4) * 8;
            u32 hv[4], lv[4];
#pragma unroll
            for (int jj = 0; jj < 4; ++jj) {
                float wA = src[(size_t)(k0 + 2 * jj) * HD + col];
                float wB = src[(size_t)(k0 + 2 * jj + 1) * HD + col];
                u16 ha = bf16rn(wA), hb = bf16rn(wB);
                u16 la = bf16rn(wA - u2f((u32)ha << 16));
                u16 lb = bf16rn(wB - u2f((u32)hb << 16));
                hv[jj] = (u32)ha | ((u32)hb << 16);
                lv[jj] = (u32)la | ((u32)lb << 16);
            }
            size_t off = ((size_t)(c * 8 + n) * 64 + lane) * 8;
            *(uint4*)(dh + off) = make_uint4(hv[0], hv[1], hv[2], hv[3]);
            *(uint4*)(dl + off) = make_uint4(lv[0], lv[1], lv[2], lv[3]);
        }
    }
}

// ---------- paired gates table ----------
__global__ void gate_table_k(const float* __restrict__ We1, const float* __restrict__ be1,
                             const float* __restrict__ We2, const float* __restrict__ be2,
                             float2* __restrict__ gt2) {
    int row = blockIdx.x;
    int l = row / (NBIN + 1);
    int i = row % (NBIN + 1);
    int j = threadIdx.x;
    float d = (CUTOFFF / NBIN) * (float)i;
    __shared__ float h1[HD];
    const float* w1 = We1 + (size_t)l * 16 * HD;
    float acc = be1[l * HD + j];
#pragma unroll
    for (int k = 0; k < 16; ++k) {
        float dd = d - 0.25f * (float)k;
        float es = __builtin_amdgcn_exp2f(-dd * dd * 8.0f * 1.44269504088896341f);
        acc = fmaf(es, w1[k * HD + j], acc);
    }
    h1[j] = sspf(acc);
    __syncthreads();
    const float* w2 = We2 + (size_t)l * HD * HD;
    float acc2 = be2[l * HD + j];
    for (int k = 0; k < HD; ++k) acc2 = fmaf(h1[k], w2[k * HD + j], acc2);
    float sc = 1.f - sigf(5.f * (d - (CUTOFFF - 1.5f)));
    float val = acc2 * sc;
    float2* base = gt2 + (size_t)l * NBIN * HD;
    if (i < NBIN) base[(size_t)i * HD + j].x = val;
    if (i > 0)    base[(size_t)(i - 1) * HD + j].y = val;
}

// ---------- layer-0 constant gate ----------
__global__ void gate0_k(const float* __restrict__ gW2, const float* __restrict__ gb1,
                        const float* __restrict__ gb2, float* __restrict__ g0v) {
    int j = threadIdx.x;
    __shared__ float h[HD];
    h[j] = sspf(gb1[j]);
    __syncthreads();
    float acc = gb2[j];
    for (int k = 0; k < HD; ++k) acc = fmaf(h[k], gW2[k * HD + j], acc);
    g0v[j] = sigf(acc);
}

// ---------- CSR sort ----------
__global__ __launch_bounds__(256) void hist_k(const int* __restrict__ pe, u32* __restrict__ cnt) {
    int e = blockIdx.x * 256 + threadIdx.x;
    if (e < NEDGE) atomic_add_u(&cnt[pe[2 * e + 1]], 1u);
}
__global__ __launch_bounds__(256) void bsum_k(const u32* __restrict__ cnt, u32* __restrict__ bsum) {
    int i = blockIdx.x * 256 + threadIdx.x;
    int v = (i < NPROBE) ? (int)cnt[i] : 0;
#pragma unroll
    for (int d = 1; d < 64; d <<= 1) v += __shfl_xor(v, d);
    __shared__ int wsum[4];
    if ((threadIdx.x & 63) == 0) wsum[threadIdx.x >> 6] = v;
    __syncthreads();
    if (threadIdx.x == 0) bsum[blockIdx.x] = (u32)(wsum[0] + wsum[1] + wsum[2] + wsum[3]);
}
__global__ __launch_bounds__(512) void bscan_k(u32* __restrict__ bsum) {
    __shared__ u32 s[512];
    int t = threadIdx.x;
    u32 v = (t < NSBLK) ? bsum[t] : 0u;
    s[t] = v;
    __syncthreads();
    for (int d = 1; d < 512; d <<= 1) {
        u32 x = (t >= d) ? s[t - d] : 0u;
        __syncthreads();
        s[t] += x;
        __syncthreads();
    }
    if (t < NSBLK) bsum[t] = s[t] - v;
}
__global__ __launch_bounds__(256) void cur_k(const u32* __restrict__ cnt,
                                             const u32* __restrict__ bsum, u32* __restrict__ cur) {
    __shared__ u32 s[256];
    int b = blockIdx.x, t = threadIdx.x;
    int i = b * 256 + t;
    u32 v = (i < NPROBE) ? cnt[i] : 0u;
    s[t] = v;
    __syncthreads();
    for (int d = 1; d < 256; d <<= 1) {
        u32 x = (t >= d) ? s[t - d] : 0u;
        __syncthreads();
        s[t] += x;
        __syncthreads();
    }
    if (i < NPROBE) cur[i] = bsum[b] + s[t] - v;
}
__global__ __launch_bounds__(256) void scatter_k(const int* __restrict__ pe,
                                                 u32* __restrict__ cur, u32* __restrict__ eord) {
    int e = blockIdx.x * 256 + threadIdx.x;
    if (e < NEDGE) {
        u32 pos = atomic_add_u(&cur[pe[2 * e + 1]], 1u);
        eord[pos] = (u32)e;
    }
}

// ---------- atom projection: Xab (bf16) ----------
#define ABLK 313
__global__ __launch_bounds__(NT, 4) void gemm_atoms_k(const float* __restrict__ atom_rep,
                                                      const u16* __restrict__ Wb,
                                                      const float* __restrict__ bn1,
                                                      u16* __restrict__ Xab) {
    __shared__ u16 ldsH[MT * 128];
    __shared__ u16 ldsL[MT * 128];
    int l = blockIdx.x / ABLK;
    int mb = blockIdx.x % ABLK;
    const float* A = atom_rep + (size_t)l * NATOM * HD;
    const u16* W = Wb + (size_t)(2 * l) * 2 * PLANE;
    u16* outp = Xab + (size_t)l * NATOM * HD;
    int m0 = mb * MT, t = threadIdx.x;
    stage_split(A, NATOM, m0, t, ldsH, ldsL);
    bar_lds();
    int lane = t & 63, wid = t >> 6;
    int l15 = lane & 15, lq = lane >> 4;
    int col = wid * 16 + l15;
    f32x4 acc[4] = {};
    mma_slice(ldsH, ldsL, lane, wid, W, acc);
    float bv = bn1[l * HD + col];
#pragma unroll
    for (int m = 0; m < 4; ++m) {
#pragma unroll
        for (int r = 0; r < 4; ++r) {
            int row = m0 + m * 16 + lq * 4 + r;
            if (row < NATOM) outp[(size_t)row * HD + col] = bf16rn(acc[m][r] + bv);
        }
    }
}

// ---------- edge kernel helpers ----------
__device__ __forceinline__ int rho(int r) {
    return ((r >> 2) & 3) * 16 + ((r >> 4) << 2) + (r & 3);
}

__device__ __forceinline__ void gather_edge(
        int e0, int t, const u16* __restrict__ Xab, const u16* __restrict__ Xp,
        const int* __restrict__ pe, const u32* __restrict__ eord,
        const float* __restrict__ dist,
        u32* mix_s, float* fr_s, float* sum) {
    int r = t >> 3, q = t & 7;
    int e = (int)eord[e0 + r];
    int snd = pe[2 * e], rcv = pe[2 * e + 1];
    if (q == 0) {
        float x = dist[e] * ((float)NBIN / CUTOFFF);
        int i = (int)x;
        i = i < (NBIN - 1) ? i : (NBIN - 1);
        fr_s[r] = x - (float)i;
        mix_s[r] = ((u32)rcv << 11) | (u32)i;
    }
    const uint4* xa4 = (const uint4*)(Xab + (size_t)snd * HD + q * 16);
    u32 aw[8];
    *(uint4*)aw = xa4[0];
    *(uint4*)(aw + 4) = xa4[1];
    u32 pw[8];
    if (Xp) {
        const uint4* xp4 = (const uint4*)(Xp + (size_t)rcv * HD + q * 16);
        *(uint4*)pw = xp4[0];
        *(uint4*)(pw + 4) = xp4[1];
    }
#pragma unroll
    for (int w = 0; w < 8; ++w) {
        float ae = u2f(aw[w] << 16), ao = u2f(aw[w] & 0xffff0000u);
        if (Xp) {
            ae += u2f(pw[w] << 16);
            ao += u2f(pw[w] & 0xffff0000u);
        }
        sum[2 * w] = ae;
        sum[2 * w + 1] = ao;
    }
}

// carry-chained run merge over 16 consecutive sorted edges per thread
__device__ __forceinline__ void edge_out(const f32x4 acc[4], const u32* mix_s,
        const float* fr_s, const float2* __restrict__ gt2,
        float bb, int col, int lq, float* __restrict__ msgsum) {
    float carry = 0.f;
    int rcc = -1;
#pragma unroll
    for (int m = 3; m >= 0; --m) {
        int ebase = lq * 16 + m * 4;
        float vals[4];
        int rc[4];
#pragma unroll
        for (int r = 0; r < 4; ++r) {
            u32 mx = mix_s[ebase + r];
            rc[r] = (int)(mx >> 11);
            float2 g2 = gt2[(size_t)(mx & 2047u) * HD + col];
            vals[r] = (acc[m][r] + bb) * fmaf(g2.y - g2.x, fr_s[ebase + r], g2.x);
        }
        if (rcc == rc[3]) vals[3] += carry;
        else if (rcc >= 0) atomic_add_f(msgsum + (size_t)rcc * HD + col, carry);
#pragma unroll
        for (int r = 3; r >= 1; --r) {
            if (rc[r] == rc[r - 1]) vals[r - 1] += vals[r];
            else atomic_add_f(msgsum + (size_t)rc[r] * HD + col, vals[r]);
        }
        carry = vals[0];
        rcc = rc[0];
    }
    atomic_add_f(msgsum + (size_t)rcc * HD + col, carry);
}

// ---------- edge kernel: single bf16 A plane, 2-MFMA ----------
__global__ __launch_bounds__(NT, 4) void edge_msg_k(
        const u16* __restrict__ Xab, const u16* __restrict__ Xp,
        const u16* __restrict__ W2b, const float* __restrict__ bn2,
        const float2* __restrict__ gt2, const float* __restrict__ dist,
        const int* __restrict__ pe, const u32* __restrict__ eord,
        float* __restrict__ msgsum) {
    __shared__ u16 ldsA[MT * 128];
    __shared__ u32 mix_s[MT];
    __shared__ float fr_s[MT];
    int t = threadIdx.x;
    int lane = t & 63, wid = t >> 6;
    int l15 = lane & 15, lq = lane >> 4;
    int col = wid * 16 + l15;
    const int nb = NEDGE / MT;               // 6250
    int e0 = bswz(blockIdx.x, nb) * MT;

    bf16x8 Bh[4], Bl[4];
    load_bfrags(W2b, lane, wid, Bh, Bl);
    float bb = bn2[col];

    float s0[16];
    gather_edge(e0, t, Xab, Xp, pe, eord, dist, mix_s, fr_s, s0);
    {
        float h[16];
#pragma unroll
        for (int k = 0; k < 16; ++k) h[k] = sspf(s0[k]);
        pack_plane(h, rho(t >> 3), t & 7, ldsA);
    }
    bar_lds();

    f32x4 acc[4] = {};
    mma_slice_a1(ldsA, lane, Bh, Bl, acc);
    edge_out(acc, mix_s, fr_s, gt2, bb, col, lq, msgsum);
}

// ---------- fused probe update: interleaved gate(2-term)/trans(3-term) MLPs ----------
__global__ __launch_bounds__(NT, 2) void probe_update_k(
        const float* ps, const float* msgsum, float* msgzero,
        const u16* __restrict__ gW1b, const float* __restrict__ gb1,
        const u16* __restrict__ gW2b, const float* __restrict__ gb2,
        const u16* __restrict__ tW1b, const float* __restrict__ tb1,
        const u16* __restrict__ tW2b, const float* __restrict__ tb2,
        const u16* __restrict__ W3b,
        const u16* __restrict__ rW1b, const float* __restrict__ rb1,
        const float* __restrict__ rW2, const float* __restrict__ rb2,
        const float* __restrict__ g0v,
        float* psout, u16* __restrict__ xpout, float* __restrict__ outp) {
    __shared__ u16 ldsH[MT * 128];   // trans hi
    __shared__ u16 ldsL[MT * 128];   // trans lo
    __shared__ u16 ldsG[MT * 128];   // gate plane (2-term)
    __shared__ float parts[MT][9];
    int m0 = blockIdx.x * MT, t = threadIdx.x;
    int lane = t & 63, wid = t >> 6;
    int l15 = lane & 15, lq = lane >> 4;
    int col = wid * 16 + l15;
    bool hasGate = (g0v == nullptr);
    bool isW3 = (W3b != nullptr);
    bool isRd = (rW1b != nullptr);

    // P0: gather both operands, pack both, fused re-zero
    float sm[16];
    gather_rows(msgsum, NPROBE, m0, t, sm);
    float sp[16];
    if (hasGate) gather_rows(ps, NPROBE, m0, t, sp);
    pack_store(sm, t >> 3, t & 7, ldsH, ldsL);
    if (hasGate) pack_plane(sp, t >> 3, t & 7, ldsG);
    if (msgzero) zero_rows(msgzero, NPROBE, m0, t);
    bar_lds();

    // P1: both first-layer GEMMs (independent buffers -> overlapped latency)
    f32x4 g[4] = {};
    f32x4 tv[4] = {};
    mma_slice(ldsH, ldsL, lane, wid, tW1b, tv);
    if (hasGate) mma_w_a1(ldsG, lane, wid, gW1b, g);
    bar_lds();

    // P2: both hidden activations back to LDS
    h_store(ldsH, ldsL, wid, lane, tv, tb1);
    if (hasGate) h_plane(ldsG, wid, lane, g, gb1);
    bar_lds();

    // P3: both second-layer GEMMs
#pragma unroll
    for (int m = 0; m < 4; ++m) tv[m] = (f32x4){0.f, 0.f, 0.f, 0.f};
    mma_slice(ldsH, ldsL, lane, wid, tW2b, tv);
    if (hasGate) {
#pragma unroll
        for (int m = 0; m < 4; ++m) g[m] = (f32x4){0.f, 0.f, 0.f, 0.f};
        mma_w_a1(ldsG, lane, wid, gW2b, g);
        float gb2v = gb2[col];
#pragma unroll
        for (int m = 0; m < 4; ++m)
#pragma unroll
            for (int r = 0; r < 4; ++r) g[m][r] = sigf(g[m][r] + gb2v);
    } else {
        float gv = g0v[col];
#pragma unroll
        for (int m = 0; m < 4; ++m)
#pragma unroll
            for (int r = 0; r < 4; ++r) g[m][r] = gv;
    }
    bool proj = isW3 || isRd;
    if (proj) bar_lds();   // all LDS reads done before overwrite

    // P4: combine ps_new = ps*g + (1-g)*t
    float tb2v = tb2[col];
#pragma unroll
    for (int m = 0; m < 4; ++m) {
#pragma unroll
        for (int r = 0; r < 4; ++r) {
            int row = m0 + m * 16 + lq * 4 + r;
            float val = 0.f;
            if (row < NPROBE) {
                size_t idx = (size_t)row * HD + col;
                float tval = tv[m][r] + tb2v;
                float pv = hasGate ? ps[idx] : 0.f;
                val = fmaf(pv - tval, g[m][r], tval);
                if (!isRd) psout[idx] = val;
            }
            if (isW3) v_plane(ldsG, wid, lane, m, r, val);       // attenuated downstream
            else if (isRd) v_store(ldsH, ldsL, wid, lane, m, r, val);  // terminal: hi/lo
        }
    }
    if (!proj) return;
    bar_lds();

    // P5: projection / readout
    if (isW3) {
        f32x4 a[4] = {};
        mma_w_a1(ldsG, lane, wid, W3b, a);
#pragma unroll
        for (int m = 0; m < 4; ++m)
#pragma unroll
            for (int r = 0; r < 4; ++r) {
                int row = m0 + m * 16 + lq * 4 + r;
                if (row < NPROBE) xpout[(size_t)row * HD + col] = bf16rn(a[m][r]);
            }
    } else {
        f32x4 a[4] = {};
        mma_slice(ldsH, ldsL, lane, wid, rW1b, a);
        float rb1v = rb1[col], w2v = rW2[col];
#pragma unroll
        for (int m = 0; m < 4; ++m)
#pragma unroll
            for (int r = 0; r < 4; ++r) {
                float p = sspf(a[m][r] + rb1v) * w2v;
                p += __shfl_xor(p, 1, 16);
                p += __shfl_xor(p, 2, 16);
                p += __shfl_xor(p, 4, 16);
                p += __shfl_xor(p, 8, 16);
                if (l15 == 0) parts[m * 16 + lq * 4 + r][wid] = p;
            }
        bar_lds();
        if (t < MT) {
            int row = m0 + t;
            if (row < NPROBE) {
                float s = rb2[0];
#pragma unroll
                for (int w = 0; w < 8; ++w) s += parts[t][w];
                outp[row] = s;
            }
        }
    }
}

// ---------- launcher ----------
extern "C" void kernel_launch(void* const* d_in, const int* in_sizes, int n_in,
                              void* d_out, int out_size, void* d_ws, size_t ws_size,
                              hipStream_t stream) {
    const float* atom_rep = (const float*)d_in[0];
    const float* dist     = (const float*)d_in[1];
    const float* We1 = (const float*)d_in[2];
    const float* be1 = (const float*)d_in[3];
    const float* We2 = (const float*)d_in[4];
    const float* be2 = (const float*)d_in[5];
    const float* Wn1 = (const float*)d_in[6];
    const float* bn1 = (const float*)d_in[7];
    const float* Wn2 = (const float*)d_in[8];
    const float* bn2 = (const float*)d_in[9];
    const float* gW1 = (const float*)d_in[10];
    const float* gb1 = (const float*)d_in[11];
    const float* gW2 = (const float*)d_in[12];
    const float* gb2 = (const float*)d_in[13];
    const float* tW1 = (const float*)d_in[14];
    const float* tb1 = (const float*)d_in[15];
    const float* tW2 = (const float*)d_in[16];
    const float* tb2 = (const float*)d_in[17];
    const float* rW1 = (const float*)d_in[18];
    const float* rb1 = (const float*)d_in[19];
    const float* rW2 = (const float*)d_in[20];
    const float* rb2 = (const float*)d_in[21];
    const int*   pe  = (const int*)d_in[22];
    float* out = (float*)d_out;

    float* ws = (float*)d_ws;
    float* ps     = ws;                          // 12,800,000 f
    float* msgsum = ps + 12800000u;              // 12,800,000 f
    float2* gt2   = (float2*)(msgsum + 12800000u);               // 3*NBIN*HD float2
    float* g0v    = (float*)(gt2 + (size_t)NLAYER * NBIN * HD);  // 128 f
    u16*   Wb     = (u16*)(g0v + 128);           // 22*2*PLANE u16
    u16*   Xp16   = Wb + 22 * 2 * PLANE;         // 12,800,000 u16
    u16*   Xab    = Xp16 + 12800000u;            // 3*2,560,000 u16
    u32*   cnt    = (u32*)(Xab + 7680000u);
    u32*   bsum   = cnt + NPROBE;                // NSBLK
    u32*   cur    = bsum + 512;
    u32*   eord   = cur + NPROBE;

    const int PBLK = (NPROBE + MT - 1) / MT;   // 1563
    const int EBLK = NEDGE / MT;               // 6250
    const int TBLK = (NEDGE + 255) / 256;      // 1563

    hipMemsetAsync(cnt, 0, (size_t)NPROBE * 4, stream);
    hipMemsetAsync(msgsum, 0, 12800000ull * 4, stream);
    convert_w_k<<<22, 256, 0, stream>>>(Wn1, Wn2, gW1, gW2, tW1, tW2, rW1, Wb);
    gate_table_k<<<NLAYER * (NBIN + 1), HD, 0, stream>>>(We1, be1, We2, be2, gt2);
    gate0_k<<<1, HD, 0, stream>>>(gW2, gb1, gb2, g0v);
    hist_k<<<TBLK, 256, 0, stream>>>(pe, cnt);
    bsum_k<<<NSBLK, 256, 0, stream>>>(cnt, bsum);
    bscan_k<<<1, 512, 0, stream>>>(bsum);
    cur_k<<<NSBLK, 256, 0, stream>>>(cnt, bsum, cur);
    scatter_k<<<TBLK, 256, 0, stream>>>(pe, cur, eord);
    gemm_atoms_k<<<NLAYER * ABLK, NT, 0, stream>>>(atom_rep, Wb, bn1, Xab);

    for (int l = 0; l < NLAYER; ++l) {
        edge_msg_k<<<EBLK, NT, 0, stream>>>(Xab + (size_t)l * NATOM * HD,
                                            (l == 0) ? nullptr : Xp16,
                                            Wb + (size_t)(6 + l) * 2 * PLANE,
                                            bn2 + l * HD,
                                            gt2 + (size_t)l * NBIN * HD,
                                            dist, pe, eord, msgsum);
        const u16* W3  = (l < NLAYER - 1) ? Wb + (size_t)(2 * (l + 1) + 1) * 2 * PLANE : nullptr;
        const u16* RW1 = (l == NLAYER - 1) ? Wb + (size_t)21 * 2 * PLANE : nullptr;
        float* mz = (l < NLAYER - 1) ? msgsum : nullptr;
        probe_update_k<<<PBLK, NT, 0, stream>>>(ps, msgsum, mz,
                                                Wb + (size_t)(9 + l) * 2 * PLANE, gb1 + l * HD,
                                                Wb + (size_t)(12 + l) * 2 * PLANE, gb2 + l * HD,
                                                Wb + (size_t)(15 + l) * 2 * PLANE, tb1 + l * HD,
                                                Wb + (size_t)(18 + l) * 2 * PLANE, tb2 + l * HD,
                                                W3, RW1, rb1, rW2, rb2,
                                                (l == 0) ? g0v : nullptr,
                                                ps, Xp16, out);
    }
}

// Round 17
// 601.561 us; speedup vs baseline: 1.1053x; 1.1053x over previous
//
#include <hip/hip_runtime.h>

#define NLAYER 3
#define NATOM 20000
#define NPROBE 100000
#define NEDGE 400000
#define HD 128
#define NBIN 2048
#define CUTOFFF 4.0f
#define PLANE 16384   // ushorts per bf16 plane (128x128)
#define MT 64         // row tile
#define NT 512        // threads per block (8 waves)
#define NSBLK ((NPROBE + 255) / 256)   // 391 scan blocks

typedef unsigned int u32;
typedef unsigned short u16;
typedef __attribute__((ext_vector_type(8))) short bf16x8;
typedef __attribute__((ext_vector_type(4))) float f32x4;

// ---------- math helpers ----------
__device__ __forceinline__ float sspf(float x) {
    float e = __builtin_amdgcn_exp2f(fminf(x, 80.f) * 1.44269504088896341f);
    return 0.69314718055994531f * (__builtin_amdgcn_logf(1.f + e) - 1.f);
}
__device__ __forceinline__ float sigf(float x) {
    return 1.f / (1.f + __builtin_amdgcn_exp2f(-x * 1.44269504088896341f));
}
__device__ __forceinline__ void atomic_add_f(float* p, float v) {
    __hip_atomic_fetch_add(p, v, __ATOMIC_RELAXED, __HIP_MEMORY_SCOPE_AGENT);
}
__device__ __forceinline__ u32 atomic_add_u(u32* p, u32 v) {
    return __hip_atomic_fetch_add(p, v, __ATOMIC_RELAXED, __HIP_MEMORY_SCOPE_AGENT);
}
__device__ __forceinline__ u32 f2u(float f) { union { float f; u32 u; } x; x.f = f; return x.u; }
__device__ __forceinline__ float u2f(u32 u) { union { float f; u32 u; } x; x.u = u; return x.f; }
__device__ __forceinline__ u16 bf16rn(float f) {
    u32 u = f2u(f);
    u32 r = u + 0x7fffu + ((u >> 16) & 1u);
    return (u16)(r >> 16);
}
// pack 2 floats -> 1 u32 of rounded bf16 pair
__device__ __forceinline__ u32 bf16pair(float x, float y) {
    u32 ux = f2u(x);
    u32 hx = (ux + 0x7fffu + ((ux >> 16) & 1u)) >> 16;
    u32 uy = f2u(y);
    u32 hy = (uy + 0x7fffu + ((uy >> 16) & 1u)) & 0xffff0000u;
    return hx | hy;
}
__device__ __forceinline__ void split_pair(float x, float y, u32& hi, u32& lo) {
    u32 ux = f2u(x);
    u32 hx = (ux + 0x7fffu + ((ux >> 16) & 1u)) & 0xffff0000u;
    float lxf = x - u2f(hx);
    u32 uy = f2u(y);
    u32 hy = (uy + 0x7fffu + ((uy >> 16) & 1u)) & 0xffff0000u;
    float lyf = y - u2f(hy);
    hi = (hx >> 16) | hy;
    lo = (f2u(lxf) >> 16) | (f2u(lyf) & 0xffff0000u);
}

// LDS-only barrier: do NOT drain vmcnt (atomics / prefetch loads stay in flight).
__device__ __forceinline__ void bar_lds() {
    asm volatile("s_waitcnt lgkmcnt(0)" ::: "memory");
    __builtin_amdgcn_s_barrier();
}

// bijective XCD-chunked swizzle (m204)
__device__ __forceinline__ int bswz(int b, int nb) {
    int q = nb >> 3, r = nb & 7;
    int x = b & 7, o = b >> 3;
    return (x < r ? x * (q + 1) : r * (q + 1) + (x - r) * q) + o;
}

// ---------- MFMA core: weight-stationary column slice ----------
__device__ __forceinline__ void load_bfrags(const u16* __restrict__ Wb, int lane, int wid,
                                            bf16x8 Bh[4], bf16x8 Bl[4]) {
    const bf16x8* Bhp = (const bf16x8*)Wb;
    const bf16x8* Blp = (const bf16x8*)(Wb + PLANE);
#pragma unroll
    for (int c = 0; c < 4; ++c) {
        Bh[c] = Bhp[(size_t)(c * 8 + wid) * 64 + lane];
        Bl[c] = Blp[(size_t)(c * 8 + wid) * 64 + lane];
    }
}

// 3-term (hi/lo A planes) — probe/atoms path
__device__ __forceinline__ void mma_slice_pre(const u16* __restrict__ ldsH,
                                              const u16* __restrict__ ldsL,
                                              int lane, const bf16x8 Bh[4], const bf16x8 Bl[4],
                                              f32x4 acc[4]) {
    int l15 = lane & 15, kq = lane >> 4;
#pragma unroll
    for (int m = 0; m < 4; ++m) {
        int row = m * 16 + l15;
        int s = row & 7;
        const u16* hp = ldsH + row * 128;
        const u16* lp = ldsL + row * 128;
#pragma unroll
        for (int c = 0; c < 4; ++c) {
            int off = ((c * 4 + kq) ^ s) << 3;
            bf16x8 Ah = *(const bf16x8*)(hp + off);
            bf16x8 Al = *(const bf16x8*)(lp + off);
            acc[m] = __builtin_amdgcn_mfma_f32_16x16x32_bf16(Ah, Bh[c], acc[m], 0, 0, 0);
            acc[m] = __builtin_amdgcn_mfma_f32_16x16x32_bf16(Al, Bh[c], acc[m], 0, 0, 0);
            acc[m] = __builtin_amdgcn_mfma_f32_16x16x32_bf16(Ah, Bl[c], acc[m], 0, 0, 0);
        }
    }
}

__device__ __forceinline__ void mma_slice(const u16* __restrict__ ldsH,
                                          const u16* __restrict__ ldsL,
                                          int lane, int wid,
                                          const u16* __restrict__ Wb,
                                          f32x4 acc[4]) {
    bf16x8 Bh[4], Bl[4];
    load_bfrags(Wb, lane, wid, Bh, Bl);
    mma_slice_pre(ldsH, ldsL, lane, Bh, Bl, acc);
}

// 2-term (single bf16 A plane, hi/lo B) — edge path
__device__ __forceinline__ void mma_slice_a1(const u16* __restrict__ ldsA,
                                             int lane, const bf16x8 Bh[4], const bf16x8 Bl[4],
                                             f32x4 acc[4]) {
    int l15 = lane & 15, kq = lane >> 4;
#pragma unroll
    for (int m = 0; m < 4; ++m) {
        int row = m * 16 + l15;
        int s = row & 7;
        const u16* ap = ldsA + row * 128;
#pragma unroll
        for (int c = 0; c < 4; ++c) {
            int off = ((c * 4 + kq) ^ s) << 3;
            bf16x8 Ah = *(const bf16x8*)(ap + off);
            acc[m] = __builtin_amdgcn_mfma_f32_16x16x32_bf16(Ah, Bh[c], acc[m], 0, 0, 0);
            acc[m] = __builtin_amdgcn_mfma_f32_16x16x32_bf16(Ah, Bl[c], acc[m], 0, 0, 0);
        }
    }
}

// ---------- staging helpers ----------
__device__ __forceinline__ void pack_store(const float* v, int row, int q,
                                           u16* ldsH, u16* ldsL) {
    int s = row & 7;
#pragma unroll
    for (int h = 0; h < 2; ++h) {
        u32 hv[4], lv[4];
#pragma unroll
        for (int k = 0; k < 4; ++k)
            split_pair(v[8 * h + 2 * k], v[8 * h + 2 * k + 1], hv[k], lv[k]);
        int gc = q * 2 + h;
        int off = row * 128 + ((gc ^ s) << 3);
        *(uint4*)(ldsH + off) = make_uint4(hv[0], hv[1], hv[2], hv[3]);
        *(uint4*)(ldsL + off) = make_uint4(lv[0], lv[1], lv[2], lv[3]);
    }
}

// single-plane bf16 pack (edge A)
__device__ __forceinline__ void pack_plane(const float* v, int row, int q, u16* ldsA) {
    int s = row & 7;
#pragma unroll
    for (int h = 0; h < 2; ++h) {
        u32 w0 = bf16pair(v[8 * h + 0], v[8 * h + 1]);
        u32 w1 = bf16pair(v[8 * h + 2], v[8 * h + 3]);
        u32 w2 = bf16pair(v[8 * h + 4], v[8 * h + 5]);
        u32 w3 = bf16pair(v[8 * h + 6], v[8 * h + 7]);
        int gc = q * 2 + h;
        *(uint4*)(ldsA + row * 128 + ((gc ^ s) << 3)) = make_uint4(w0, w1, w2, w3);
    }
}

__device__ __forceinline__ void gather_rows(const float* __restrict__ A, int M,
                                            int m0, int t, float* v) {
    int r = t >> 3, q = t & 7;
    int row = m0 + r;
    bool ok = row < M;
    const float4* src = (const float4*)(A + (size_t)row * HD + q * 16);
#pragma unroll
    for (int j = 0; j < 4; ++j) {
        float4 x = ok ? src[j] : make_float4(0.f, 0.f, 0.f, 0.f);
        v[4 * j] = x.x; v[4 * j + 1] = x.y; v[4 * j + 2] = x.z; v[4 * j + 3] = x.w;
    }
}
__device__ __forceinline__ void zero_rows(float* A, int M, int m0, int t) {
    int r = t >> 3, q = t & 7;
    int row = m0 + r;
    if (row < M) {
        float4* dst = (float4*)(A + (size_t)row * HD + q * 16);
        float4 z = make_float4(0.f, 0.f, 0.f, 0.f);
#pragma unroll
        for (int j = 0; j < 4; ++j) dst[j] = z;
    }
}
__device__ __forceinline__ void stage_split(const float* __restrict__ A, int M,
                                            int m0, int t, u16* ldsH, u16* ldsL) {
    float v[16];
    gather_rows(A, M, m0, t, v);
    pack_store(v, t >> 3, t & 7, ldsH, ldsL);
}

// write ssp(acc+bias) back to planes (own col-slice, all rows)
__device__ __forceinline__ void h_store(u16* ldsH, u16* ldsL, int wid, int lane,
                                        const f32x4 acc[4], const float* __restrict__ bias) {
    int l15 = lane & 15, lq = lane >> 4;
    int col = wid * 16 + l15;
    float bb = bias[col];
    int gc = col >> 3, wg = col & 7;
#pragma unroll
    for (int m = 0; m < 4; ++m) {
#pragma unroll
        for (int r = 0; r < 4; ++r) {
            int row = m * 16 + lq * 4 + r;
            float h = sspf(acc[m][r] + bb);
            u32 u = f2u(h);
            u32 hh = (u + 0x7fffu + ((u >> 16) & 1u)) & 0xffff0000u;
            float lf = h - u2f(hh);
            int off = row * 128 + ((gc ^ (row & 7)) << 3) + wg;
            ldsH[off] = (u16)(hh >> 16);
            ldsL[off] = (u16)(f2u(lf) >> 16);
        }
    }
}
__device__ __forceinline__ void v_store(u16* ldsH, u16* ldsL, int wid, int lane,
                                        int m, int r, float val) {
    int l15 = lane & 15, lq = lane >> 4;
    int col = wid * 16 + l15;
    int gc = col >> 3, wg = col & 7;
    int row = m * 16 + lq * 4 + r;
    u32 u = f2u(val);
    u32 hh = (u + 0x7fffu + ((u >> 16) & 1u)) & 0xffff0000u;
    float lf = val - u2f(hh);
    int off = row * 128 + ((gc ^ (row & 7)) << 3) + wg;
    ldsH[off] = (u16)(hh >> 16);
    ldsL[off] = (u16)(f2u(lf) >> 16);
}

// ---------- weight conversion ----------
__global__ void convert_w_k(const float* __restrict__ Wn1, const float* __restrict__ Wn2,
                            const float* __restrict__ gW1, const float* __restrict__ gW2,
                            const float* __restrict__ tW1, const float* __restrict__ tW2,
                            const float* __restrict__ rW1, u16* __restrict__ Wb) {
    int m = blockIdx.x;
    const float* src;
    if (m < 6)       src = Wn1 + (size_t)(m >> 1) * (2 * HD * HD) + (size_t)(m & 1) * (HD * HD);
    else if (m < 9)  src = Wn2 + (size_t)(m - 6) * HD * HD;
    else if (m < 12) src = gW1 + (size_t)(m - 9) * HD * HD;
    else if (m < 15) src = gW2 + (size_t)(m - 12) * HD * HD;
    else if (m < 18) src = tW1 + (size_t)(m - 15) * HD * HD;
    else if (m < 21) src = tW2 + (size_t)(m - 18) * HD * HD;
    else             src = rW1;
    int t = threadIdx.x;
    int lane = t & 63, nn = t >> 6;
    u16* dh = Wb + (size_t)m * (2 * PLANE);
    u16* dl = dh + PLANE;
    for (int c = 0; c < 4; ++c) {
        for (int hh = 0; hh < 2; ++hh) {
            int n = nn + hh * 4;
            int col = n * 16 + (lane & 15);
            int k0 = c * 32 + (lane >> 4) * 8;
            u32 hv[4], lv[4];
#pragma unroll
            for (int jj = 0; jj < 4; ++jj) {
                float wA = src[(size_t)(k0 + 2 * jj) * HD + col];
                float wB = src[(size_t)(k0 + 2 * jj + 1) * HD + col];
                u16 ha = bf16rn(wA), hb = bf16rn(wB);
                u16 la = bf16rn(wA - u2f((u32)ha << 16));
                u16 lb = bf16rn(wB - u2f((u32)hb << 16));
                hv[jj] = (u32)ha | ((u32)hb << 16);
                lv[jj] = (u32)la | ((u32)lb << 16);
            }
            size_t off = ((size_t)(c * 8 + n) * 64 + lane) * 8;
            *(uint4*)(dh + off) = make_uint4(hv[0], hv[1], hv[2], hv[3]);
            *(uint4*)(dl + off) = make_uint4(lv[0], lv[1], lv[2], lv[3]);
        }
    }
}

// ---------- paired gates table ----------
__global__ void gate_table_k(const float* __restrict__ We1, const float* __restrict__ be1,
                             const float* __restrict__ We2, const float* __restrict__ be2,
                             float2* __restrict__ gt2) {
    int row = blockIdx.x;
    int l = row / (NBIN + 1);
    int i = row % (NBIN + 1);
    int j = threadIdx.x;
    float d = (CUTOFFF / NBIN) * (float)i;
    __shared__ float h1[HD];
    const float* w1 = We1 + (size_t)l * 16 * HD;
    float acc = be1[l * HD + j];
#pragma unroll
    for (int k = 0; k < 16; ++k) {
        float dd = d - 0.25f * (float)k;
        float es = __builtin_amdgcn_exp2f(-dd * dd * 8.0f * 1.44269504088896341f);
        acc = fmaf(es, w1[k * HD + j], acc);
    }
    h1[j] = sspf(acc);
    __syncthreads();
    const float* w2 = We2 + (size_t)l * HD * HD;
    float acc2 = be2[l * HD + j];
    for (int k = 0; k < HD; ++k) acc2 = fmaf(h1[k], w2[k * HD + j], acc2);
    float sc = 1.f - sigf(5.f * (d - (CUTOFFF - 1.5f)));
    float val = acc2 * sc;
    float2* base = gt2 + (size_t)l * NBIN * HD;
    if (i < NBIN) base[(size_t)i * HD + j].x = val;
    if (i > 0)    base[(size_t)(i - 1) * HD + j].y = val;
}

// ---------- layer-0 constant gate ----------
__global__ void gate0_k(const float* __restrict__ gW2, const float* __restrict__ gb1,
                        const float* __restrict__ gb2, float* __restrict__ g0v) {
    int j = threadIdx.x;
    __shared__ float h[HD];
    h[j] = sspf(gb1[j]);
    __syncthreads();
    float acc = gb2[j];
    for (int k = 0; k < HD; ++k) acc = fmaf(h[k], gW2[k * HD + j], acc);
    g0v[j] = sigf(acc);
}

// ---------- CSR sort ----------
__global__ __launch_bounds__(256) void hist_k(const int* __restrict__ pe, u32* __restrict__ cnt) {
    int e = blockIdx.x * 256 + threadIdx.x;
    if (e < NEDGE) atomic_add_u(&cnt[pe[2 * e + 1]], 1u);
}

__global__ __launch_bounds__(256) void bsum_k(const u32* __restrict__ cnt, u32* __restrict__ bsum) {
    int i = blockIdx.x * 256 + threadIdx.x;
    int v = (i < NPROBE) ? (int)cnt[i] : 0;
#pragma unroll
    for (int d = 1; d < 64; d <<= 1) v += __shfl_xor(v, d);
    __shared__ int wsum[4];
    if ((threadIdx.x & 63) == 0) wsum[threadIdx.x >> 6] = v;
    __syncthreads();
    if (threadIdx.x == 0) bsum[blockIdx.x] = (u32)(wsum[0] + wsum[1] + wsum[2] + wsum[3]);
}

__global__ __launch_bounds__(512) void bscan_k(u32* __restrict__ bsum) {
    __shared__ u32 s[512];
    int t = threadIdx.x;
    u32 v = (t < NSBLK) ? bsum[t] : 0u;
    s[t] = v;
    __syncthreads();
    for (int d = 1; d < 512; d <<= 1) {
        u32 x = (t >= d) ? s[t - d] : 0u;
        __syncthreads();
        s[t] += x;
        __syncthreads();
    }
    if (t < NSBLK) bsum[t] = s[t] - v;
}

__global__ __launch_bounds__(256) void cur_k(const u32* __restrict__ cnt,
                                             const u32* __restrict__ bsum, u32* __restrict__ cur) {
    __shared__ u32 s[256];
    int b = blockIdx.x, t = threadIdx.x;
    int i = b * 256 + t;
    u32 v = (i < NPROBE) ? cnt[i] : 0u;
    s[t] = v;
    __syncthreads();
    for (int d = 1; d < 256; d <<= 1) {
        u32 x = (t >= d) ? s[t - d] : 0u;
        __syncthreads();
        s[t] += x;
        __syncthreads();
    }
    if (i < NPROBE) cur[i] = bsum[b] + s[t] - v;
}

__global__ __launch_bounds__(256) void scatter_k(const int* __restrict__ pe,
                                                 u32* __restrict__ cur, u32* __restrict__ eord) {
    int e = blockIdx.x * 256 + threadIdx.x;
    if (e < NEDGE) {
        u32 pos = atomic_add_u(&cur[pe[2 * e + 1]], 1u);
        eord[pos] = (u32)e;
    }
}

// ---------- atom projection: Xab (bf16) = bf16rn(atom_rep @ Wn1_atom + bn1) ----------
#define ABLK 313
__global__ __launch_bounds__(NT, 4) void gemm_atoms_k(const float* __restrict__ atom_rep,
                                                      const u16* __restrict__ Wb,
                                                      const float* __restrict__ bn1,
                                                      u16* __restrict__ Xab) {
    __shared__ u16 ldsH[MT * 128];
    __shared__ u16 ldsL[MT * 128];
    int l = blockIdx.x / ABLK;
    int mb = blockIdx.x % ABLK;
    const float* A = atom_rep + (size_t)l * NATOM * HD;
    const u16* W = Wb + (size_t)(2 * l) * 2 * PLANE;
    u16* outp = Xab + (size_t)l * NATOM * HD;
    int m0 = mb * MT, t = threadIdx.x;
    stage_split(A, NATOM, m0, t, ldsH, ldsL);
    bar_lds();
    int lane = t & 63, wid = t >> 6;
    int l15 = lane & 15, lq = lane >> 4;
    int col = wid * 16 + l15;
    f32x4 acc[4] = {};
    mma_slice(ldsH, ldsL, lane, wid, W, acc);
    float bv = bn1[l * HD + col];
#pragma unroll
    for (int m = 0; m < 4; ++m) {
#pragma unroll
        for (int r = 0; r < 4; ++r) {
            int row = m0 + m * 16 + lq * 4 + r;
            if (row < NATOM) outp[(size_t)row * HD + col] = bf16rn(acc[m][r] + bv);
        }
    }
}

// ---------- edge kernel helpers ----------
__device__ __forceinline__ int rho(int r) {
    return ((r >> 2) & 3) * 16 + ((r >> 4) << 2) + (r & 3);
}

// Xab/Xp are bf16 (u16) tables; unpack+add in f32
__device__ __forceinline__ void gather_edge(
        int e0, int t, const u16* __restrict__ Xab, const u16* __restrict__ Xp,
        const int* __restrict__ pe, const u32* __restrict__ eord,
        const float* __restrict__ dist,
        u32* mix_s, float* fr_s, float* sum) {
    int r = t >> 3, q = t & 7;
    int e = (int)eord[e0 + r];
    int snd = pe[2 * e], rcv = pe[2 * e + 1];
    if (q == 0) {
        float x = dist[e] * ((float)NBIN / CUTOFFF);
        int i = (int)x;
        i = i < (NBIN - 1) ? i : (NBIN - 1);
        fr_s[r] = x - (float)i;
        mix_s[r] = ((u32)rcv << 11) | (u32)i;
    }
    const uint4* xa4 = (const uint4*)(Xab + (size_t)snd * HD + q * 16);
    u32 aw[8];
    *(uint4*)aw = xa4[0];
    *(uint4*)(aw + 4) = xa4[1];
    u32 pw[8];
    if (Xp) {
        const uint4* xp4 = (const uint4*)(Xp + (size_t)rcv * HD + q * 16);
        *(uint4*)pw = xp4[0];
        *(uint4*)(pw + 4) = xp4[1];
    }
#pragma unroll
    for (int w = 0; w < 8; ++w) {
        float ae = u2f(aw[w] << 16), ao = u2f(aw[w] & 0xffff0000u);
        if (Xp) {
            ae += u2f(pw[w] << 16);
            ao += u2f(pw[w] & 0xffff0000u);
        }
        sum[2 * w] = ae;
        sum[2 * w + 1] = ao;
    }
}

// carry-chained run merge over 16 consecutive sorted edges per thread
__device__ __forceinline__ void edge_out(const f32x4 acc[4], const u32* mix_s,
        const float* fr_s, const float2* __restrict__ gt2,
        float bb, int col, int lq, float* __restrict__ msgsum) {
    float carry = 0.f;
    int rcc = -1;
#pragma unroll
    for (int m = 3; m >= 0; --m) {
        int ebase = lq * 16 + m * 4;
        float vals[4];
        int rc[4];
#pragma unroll
        for (int r = 0; r < 4; ++r) {
            u32 mx = mix_s[ebase + r];
            rc[r] = (int)(mx >> 11);
            float2 g2 = gt2[(size_t)(mx & 2047u) * HD + col];
            vals[r] = (acc[m][r] + bb) * fmaf(g2.y - g2.x, fr_s[ebase + r], g2.x);
        }
        if (rcc == rc[3]) vals[3] += carry;
        else if (rcc >= 0) atomic_add_f(msgsum + (size_t)rcc * HD + col, carry);
#pragma unroll
        for (int r = 3; r >= 1; --r) {
            if (rc[r] == rc[r - 1]) vals[r - 1] += vals[r];
            else atomic_add_f(msgsum + (size_t)rc[r] * HD + col, vals[r]);
        }
        carry = vals[0];
        rcc = rc[0];
    }
    atomic_add_f(msgsum + (size_t)rcc * HD + col, carry);
}

// ---------- edge kernel: single bf16 A plane, 2-MFMA ----------
__global__ __launch_bounds__(NT, 4) void edge_msg_k(
        const u16* __restrict__ Xab, const u16* __restrict__ Xp,
        const u16* __restrict__ W2b, const float* __restrict__ bn2,
        const float2* __restrict__ gt2, const float* __restrict__ dist,
        const int* __restrict__ pe, const u32* __restrict__ eord,
        float* __restrict__ msgsum) {
    __shared__ u16 ldsA[MT * 128];
    __shared__ u32 mix_s[MT];
    __shared__ float fr_s[MT];
    int t = threadIdx.x;
    int lane = t & 63, wid = t >> 6;
    int l15 = lane & 15, lq = lane >> 4;
    int col = wid * 16 + l15;
    const int nb = NEDGE / MT;               // 6250
    int e0 = bswz(blockIdx.x, nb) * MT;

    bf16x8 Bh[4], Bl[4];
    load_bfrags(W2b, lane, wid, Bh, Bl);
    float bb = bn2[col];

    float s0[16];
    gather_edge(e0, t, Xab, Xp, pe, eord, dist, mix_s, fr_s, s0);
    {
        float h[16];
#pragma unroll
        for (int k = 0; k < 16; ++k) h[k] = sspf(s0[k]);
        pack_plane(h, rho(t >> 3), t & 7, ldsA);
    }
    bar_lds();

    f32x4 acc[4] = {};
    mma_slice_a1(ldsA, lane, Bh, Bl, acc);
    edge_out(acc, mix_s, fr_s, gt2, bb, col, lq, msgsum);
}

// ---------- fused probe update (single-buffer, 3-term) ----------
__global__ __launch_bounds__(NT, 4) void probe_update_k(
        const float* ps, const float* msgsum, float* msgzero,
        const u16* __restrict__ gW1b, const float* __restrict__ gb1,
        const u16* __restrict__ gW2b, const float* __restrict__ gb2,
        const u16* __restrict__ tW1b, const float* __restrict__ tb1,
        const u16* __restrict__ tW2b, const float* __restrict__ tb2,
        const u16* __restrict__ W3b,
        const u16* __restrict__ rW1b, const float* __restrict__ rb1,
        const float* __restrict__ rW2, const float* __restrict__ rb2,
        const float* __restrict__ g0v,
        float* psout, u16* __restrict__ xpout, float* __restrict__ outp) {
    __shared__ u16 ldsH[MT * 128];
    __shared__ u16 ldsL[MT * 128];
    __shared__ float parts[MT][9];
    int m0 = blockIdx.x * MT, t = threadIdx.x;
    int lane = t & 63, wid = t >> 6;
    int l15 = lane & 15, lq = lane >> 4;
    int col = wid * 16 + l15;

    f32x4 g[4] = {};
    f32x4 tv[4] = {};

    // msgsum gather issued first: latency hides under the gate MLP
    float sm[16];
    gather_rows(msgsum, NPROBE, m0, t, sm);

    if (!g0v) {
        stage_split(ps, NPROBE, m0, t, ldsH, ldsL);
        bar_lds();
        mma_slice(ldsH, ldsL, lane, wid, gW1b, g);
        bar_lds();
        h_store(ldsH, ldsL, wid, lane, g, gb1);
        bar_lds();
#pragma unroll
        for (int m = 0; m < 4; ++m) g[m] = (f32x4){0.f, 0.f, 0.f, 0.f};
        mma_slice(ldsH, ldsL, lane, wid, gW2b, g);
        float gb2v = gb2[col];
#pragma unroll
        for (int m = 0; m < 4; ++m)
#pragma unroll
            for (int r = 0; r < 4; ++r) g[m][r] = sigf(g[m][r] + gb2v);
        bar_lds();   // all reads of buffer done before overwrite
    } else {
        float gv = g0v[col];
#pragma unroll
        for (int m = 0; m < 4; ++m)
#pragma unroll
            for (int r = 0; r < 4; ++r) g[m][r] = gv;
    }

    pack_store(sm, t >> 3, t & 7, ldsH, ldsL);
    if (msgzero) zero_rows(msgzero, NPROBE, m0, t);   // after pack consumed the loads
    bar_lds();
    mma_slice(ldsH, ldsL, lane, wid, tW1b, tv);
    bar_lds();
    h_store(ldsH, ldsL, wid, lane, tv, tb1);
    bar_lds();
#pragma unroll
    for (int m = 0; m < 4; ++m) tv[m] = (f32x4){0.f, 0.f, 0.f, 0.f};
    mma_slice(ldsH, ldsL, lane, wid, tW2b, tv);

    bool proj = (W3b != nullptr) || (rW1b != nullptr);
    if (proj) bar_lds();   // tW2 reads done before v_store overwrites

    float tb2v = tb2[col];
#pragma unroll
    for (int m = 0; m < 4; ++m) {
#pragma unroll
        for (int r = 0; r < 4; ++r) {
            int row = m0 + m * 16 + lq * 4 + r;
            float val = 0.f;
            if (row < NPROBE) {
                size_t idx = (size_t)row * HD + col;
                float tval = tv[m][r] + tb2v;
                float pv = g0v ? 0.f : ps[idx];
                val = fmaf(pv - tval, g[m][r], tval);
                if (!rW1b) psout[idx] = val;
            }
            if (proj) v_store(ldsH, ldsL, wid, lane, m, r, val);
        }
    }
    if (!proj) return;
    bar_lds();

    if (W3b) {
        f32x4 a[4] = {};
        mma_slice(ldsH, ldsL, lane, wid, W3b, a);
#pragma unroll
        for (int m = 0; m < 4; ++m)
#pragma unroll
            for (int r = 0; r < 4; ++r) {
                int row = m0 + m * 16 + lq * 4 + r;
                if (row < NPROBE) xpout[(size_t)row * HD + col] = bf16rn(a[m][r]);
            }
    } else {
        f32x4 a[4] = {};
        mma_slice(ldsH, ldsL, lane, wid, rW1b, a);
        float rb1v = rb1[col], w2v = rW2[col];
#pragma unroll
        for (int m = 0; m < 4; ++m)
#pragma unroll
            for (int r = 0; r < 4; ++r) {
                float p = sspf(a[m][r] + rb1v) * w2v;
                p += __shfl_xor(p, 1, 16);
                p += __shfl_xor(p, 2, 16);
                p += __shfl_xor(p, 4, 16);
                p += __shfl_xor(p, 8, 16);
                if (l15 == 0) parts[m * 16 + lq * 4 + r][wid] = p;
            }
        bar_lds();
        if (t < MT) {
            int row = m0 + t;
            if (row < NPROBE) {
                float s = rb2[0];
#pragma unroll
                for (int w = 0; w < 8; ++w) s += parts[t][w];
                outp[row] = s;
            }
        }
    }
}

// ---------- launcher ----------
extern "C" void kernel_launch(void* const* d_in, const int* in_sizes, int n_in,
                              void* d_out, int out_size, void* d_ws, size_t ws_size,
                              hipStream_t stream) {
    const float* atom_rep = (const float*)d_in[0];
    const float* dist     = (const float*)d_in[1];
    const float* We1 = (const float*)d_in[2];
    const float* be1 = (const float*)d_in[3];
    const float* We2 = (const float*)d_in[4];
    const float* be2 = (const float*)d_in[5];
    const float* Wn1 = (const float*)d_in[6];
    const float* bn1 = (const float*)d_in[7];
    const float* Wn2 = (const float*)d_in[8];
    const float* bn2 = (const float*)d_in[9];
    const float* gW1 = (const float*)d_in[10];
    const float* gb1 = (const float*)d_in[11];
    const float* gW2 = (const float*)d_in[12];
    const float* gb2 = (const float*)d_in[13];
    const float* tW1 = (const float*)d_in[14];
    const float* tb1 = (const float*)d_in[15];
    const float* tW2 = (const float*)d_in[16];
    const float* tb2 = (const float*)d_in[17];
    const float* rW1 = (const float*)d_in[18];
    const float* rb1 = (const float*)d_in[19];
    const float* rW2 = (const float*)d_in[20];
    const float* rb2 = (const float*)d_in[21];
    const int*   pe  = (const int*)d_in[22];
    float* out = (float*)d_out;

    float* ws = (float*)d_ws;
    float* ps     = ws;                          // 12,800,000 f
    float* msgsum = ps + 12800000u;              // 12,800,000 f
    float2* gt2   = (float2*)(msgsum + 12800000u);               // 3*NBIN*HD float2
    float* g0v    = (float*)(gt2 + (size_t)NLAYER * NBIN * HD);  // 128 f
    u16*   Wb     = (u16*)(g0v + 128);           // 22*2*PLANE u16
    u16*   Xp16   = Wb + 22 * 2 * PLANE;         // 12,800,000 u16
    u16*   Xab    = Xp16 + 12800000u;            // 3*2,560,000 u16
    u32*   cnt    = (u32*)(Xab + 7680000u);
    u32*   bsum   = cnt + NPROBE;                // NSBLK
    u32*   cur    = bsum + 512;
    u32*   eord   = cur + NPROBE;

    const int PBLK = (NPROBE + MT - 1) / MT;   // 1563
    const int EBLK = NEDGE / MT;               // 6250
    const int TBLK = (NEDGE + 255) / 256;      // 1563

    hipMemsetAsync(cnt, 0, (size_t)NPROBE * 4, stream);
    hipMemsetAsync(msgsum, 0, 12800000ull * 4, stream);
    convert_w_k<<<22, 256, 0, stream>>>(Wn1, Wn2, gW1, gW2, tW1, tW2, rW1, Wb);
    gate_table_k<<<NLAYER * (NBIN + 1), HD, 0, stream>>>(We1, be1, We2, be2, gt2);
    gate0_k<<<1, HD, 0, stream>>>(gW2, gb1, gb2, g0v);
    hist_k<<<TBLK, 256, 0, stream>>>(pe, cnt);
    bsum_k<<<NSBLK, 256, 0, stream>>>(cnt, bsum);
    bscan_k<<<1, 512, 0, stream>>>(bsum);
    cur_k<<<NSBLK, 256, 0, stream>>>(cnt, bsum, cur);
    scatter_k<<<TBLK, 256, 0, stream>>>(pe, cur, eord);
    gemm_atoms_k<<<NLAYER * ABLK, NT, 0, stream>>>(atom_rep, Wb, bn1, Xab);

    for (int l = 0; l < NLAYER; ++l) {
        edge_msg_k<<<EBLK, NT, 0, stream>>>(Xab + (size_t)l * NATOM * HD,
                                            (l == 0) ? nullptr : Xp16,
                                            Wb + (size_t)(6 + l) * 2 * PLANE,
                                            bn2 + l * HD,
                                            gt2 + (size_t)l * NBIN * HD,
                                            dist, pe, eord, msgsum);
        const u16* W3  = (l < NLAYER - 1) ? Wb + (size_t)(2 * (l + 1) + 1) * 2 * PLANE : nullptr;
        const u16* RW1 = (l == NLAYER - 1) ? Wb + (size_t)21 * 2 * PLANE : nullptr;
        float* mz = (l < NLAYER - 1) ? msgsum : nullptr;
        probe_update_k<<<PBLK, NT, 0, stream>>>(ps, msgsum, mz,
                                                Wb + (size_t)(9 + l) * 2 * PLANE, gb1 + l * HD,
                                                Wb + (size_t)(12 + l) * 2 * PLANE, gb2 + l * HD,
                                                Wb + (size_t)(15 + l) * 2 * PLANE, tb1 + l * HD,
                                                Wb + (size_t)(18 + l) * 2 * PLANE, tb2 + l * HD,
                                                W3, RW1, rb1, rW2, rb2,
                                                (l == 0) ? g0v : nullptr,
                                                ps, Xp16, out);
    }
}